// Round 5
// baseline (693.230 us; speedup 1.0000x reference)
//
#include <hip/hip_runtime.h>
#include <stdint.h>

typedef __attribute__((ext_vector_type(8))) short short8;
typedef __attribute__((ext_vector_type(4))) float f32x4;
typedef __attribute__((ext_vector_type(8))) unsigned short us8;

__device__ __forceinline__ float bf2f(unsigned short s) {
  return __uint_as_float(((unsigned)s) << 16);
}
__device__ __forceinline__ unsigned short f2bf(float f) {
  unsigned u = __float_as_uint(f);
  u += 0x7fffu + ((u >> 16) & 1u);   // round-to-nearest-even
  return (unsigned short)(u >> 16);
}

// ---------------- CSR build ----------------
__global__ void gs_count_deg(const int* __restrict__ dst, int* __restrict__ cnt, int E) {
  int e = blockIdx.x * 256 + threadIdx.x;
  if (e < E) atomicAdd(&cnt[dst[e]], 1);
}

// 3-phase scan: A) per-1024-chunk local exclusive scan + chunk sum
__global__ void gs_scanA(const int* __restrict__ cnt, int* __restrict__ rp,
                         int* __restrict__ bsum, int n) {
  __shared__ int sm[256];
  const int b = blockIdx.x, t = threadIdx.x;
  const int base = b * 1024 + t * 4;
  int v[4]; int s = 0;
#pragma unroll
  for (int i = 0; i < 4; ++i) { v[i] = (base + i < n) ? cnt[base + i] : 0; s += v[i]; }
  sm[t] = s;
  __syncthreads();
  for (int off = 1; off < 256; off <<= 1) {
    int x = (t >= off) ? sm[t - off] : 0;
    __syncthreads();
    sm[t] += x;
    __syncthreads();
  }
  int run = sm[t] - s;
#pragma unroll
  for (int i = 0; i < 4; ++i) { if (base + i < n) rp[base + i] = run; run += v[i]; }
  if (t == 255) bsum[b] = sm[255];
}

// B) serial scan of chunk sums (~20 entries), total stored at bsum[nb]
__global__ void gs_scanB(int* bsum, int nb) {
  if (threadIdx.x == 0 && blockIdx.x == 0) {
    int run = 0;
    for (int i = 0; i < nb; ++i) { int v = bsum[i]; bsum[i] = run; run += v; }
    bsum[nb] = run;
  }
}

// C) add chunk offsets, replicate into cur, set rp[n]
__global__ void gs_scanC(int* __restrict__ rp, int* __restrict__ cur,
                         const int* __restrict__ bsum, int n, int nb) {
  int i = blockIdx.x * 256 + threadIdx.x;
  if (i < n) {
    int v = rp[i] + bsum[i >> 10];
    rp[i] = v;
    cur[i] = v;
  }
  if (i == n) rp[n] = bsum[nb];
}

__global__ void gs_fill_csr(const int* __restrict__ src, const int* __restrict__ dst,
                            int* __restrict__ cur, int* __restrict__ col, int E) {
  int e = blockIdx.x * 256 + threadIdx.x;
  if (e < E) {
    int pos = atomicAdd(&cur[dst[e]], 1);
    col[pos] = src[e];
  }
}

// ---------------- conversions / weight packing ----------------
__global__ void gs_f32_to_bf16(const float* __restrict__ in, unsigned short* __restrict__ out, int n4) {
  int i = blockIdx.x * 256 + threadIdx.x;
  if (i < n4) {
    float4 f = ((const float4*)in)[i];
    ushort4 o;
    o.x = f2bf(f.x); o.y = f2bf(f.y); o.z = f2bf(f.z); o.w = f2bf(f.w);
    ((ushort4*)out)[i] = o;
  }
}

// batched tiled transpose-pack: W [K x F] fp32 row-major -> WT [F x K] bf16 row-major
struct TP { const float* W; unsigned short* WT; int K, F; };
struct TP8 { TP t[8]; };

__global__ void gs_tpack8(TP8 args) {
  const TP a = args.t[blockIdx.z];
  const int k0 = blockIdx.x * 32, f0 = blockIdx.y * 32;
  if (k0 >= a.K || f0 >= a.F) return;
  __shared__ float t[32][33];
  const int tx = threadIdx.x, ty = threadIdx.y;
#pragma unroll
  for (int r = ty; r < 32; r += 8) {
    int k = k0 + r, f = f0 + tx;
    t[r][tx] = (k < a.K && f < a.F) ? a.W[(size_t)k * a.F + f] : 0.f;
  }
  __syncthreads();
#pragma unroll
  for (int r = ty; r < 32; r += 8) {
    int f = f0 + r, k = k0 + tx;
    if (f < a.F && k < a.K) a.WT[(size_t)f * a.K + k] = f2bf(t[tx][r]);
  }
}

// ---------------- wide sliced fused aggregation ----------------
// block = (node v, 512-col slice). 64 threads; each lane loads ushort8 (16 B,
// global_load_dwordx4) -> one wave-gather covers 1024 B of a row. Wave-gathers
// per edge: F=768 -> 2 (one full + one half-active), F<=512 -> 1. 4x unroll
// keeps ~4 KB in flight per wave (vs 1 KB with the 128-col ushort2 slices).
// o = mean_{nb} C[nb, cc..cc+8) (+ C[v, zoff+cc..] if zoff>=0) (+bias) (relu?)
__global__ __launch_bounds__(64)
void gs_agg_wide(const unsigned short* __restrict__ C, int ldc, int zoff,
                 const int* __restrict__ rp, const int* __restrict__ col,
                 const float* __restrict__ bias,
                 unsigned short* __restrict__ hout, float* __restrict__ fout,
                 int F, int relu) {
  const int v = blockIdx.x;
  const int l = threadIdx.x;
  const int cc = blockIdx.y * 512 + 8 * l;
  const bool act = (cc < F);
  const int s0 = rp[v], s1 = rp[v + 1];
  const float inv = 1.0f / (float)max(s1 - s0, 1);
  float a[8];
#pragma unroll
  for (int k = 0; k < 8; ++k) a[k] = 0.f;

  __shared__ int nb[64];
  for (int base = s0; base < s1; base += 64) {
    int m = min(s1 - base, 64);
    __syncthreads();
    if (l < m) nb[l] = col[base + l];
    __syncthreads();
    int j = 0;
    for (; j + 4 <= m; j += 4) {
      if (act) {
        us8 u0 = *(const us8*)(C + (size_t)nb[j + 0] * ldc + cc);
        us8 u1 = *(const us8*)(C + (size_t)nb[j + 1] * ldc + cc);
        us8 u2 = *(const us8*)(C + (size_t)nb[j + 2] * ldc + cc);
        us8 u3 = *(const us8*)(C + (size_t)nb[j + 3] * ldc + cc);
#pragma unroll
        for (int k = 0; k < 8; ++k)
          a[k] += bf2f(u0[k]) + bf2f(u1[k]) + bf2f(u2[k]) + bf2f(u3[k]);
      }
    }
    for (; j < m; ++j) {
      if (act) {
        us8 u = *(const us8*)(C + (size_t)nb[j] * ldc + cc);
#pragma unroll
        for (int k = 0; k < 8; ++k) a[k] += bf2f(u[k]);
      }
    }
  }
  if (!act) return;   // no barriers below

  float o[8];
#pragma unroll
  for (int k = 0; k < 8; ++k) o[k] = a[k] * inv;
  if (zoff >= 0) {
    us8 u = *(const us8*)(C + (size_t)v * ldc + zoff + cc);
#pragma unroll
    for (int k = 0; k < 8; ++k) o[k] += bf2f(u[k]);
  }
  if (bias) {
    float4 b0 = *(const float4*)(bias + cc);
    float4 b1 = *(const float4*)(bias + cc + 4);
    o[0] += b0.x; o[1] += b0.y; o[2] += b0.z; o[3] += b0.w;
    o[4] += b1.x; o[5] += b1.y; o[6] += b1.z; o[7] += b1.w;
  }
  if (relu) {
#pragma unroll
    for (int k = 0; k < 8; ++k) o[k] = fmaxf(o[k], 0.f);
  }
  if (hout) {
    us8 u;
#pragma unroll
    for (int k = 0; k < 8; ++k) u[k] = f2bf(o[k]);
    *(us8*)(hout + (size_t)v * F + cc) = u;
  }
  if (fout) {
    *(float4*)(fout + (size_t)v * F + cc) = make_float4(o[0], o[1], o[2], o[3]);
    *(float4*)(fout + (size_t)v * F + cc + 4) = make_float4(o[4], o[5], o[6], o[7]);
  }
}

// ---------------- GEMM: C = act(A1@B1^T [+ A2@B2^T] + bias) ----------------
// A row-major M x K (bf16), B TRANSPOSED: Nn x K row-major (bf16).
// 128x128 tile, BK=64, 4 waves of 4x4 16x16x32 MFMA (2 K-steps per iter).
// XOR chunk swizzle -> conflict-free ds_read_b128. Nn%128==0, K%64==0.
// 1-D grid swizzled: groups of MG M-tiles sweep all N-tiles (A stays L2-hot).
__global__ __launch_bounds__(256)
void gs_gemm(const unsigned short* __restrict__ A1, const unsigned short* __restrict__ A2,
             const unsigned short* __restrict__ B1, const unsigned short* __restrict__ B2,
             const float* __restrict__ bias, unsigned short* __restrict__ Hout,
             int M, int Nn, int K, int doRelu, int Mt, int Nt) {
  __shared__ unsigned short lA[128 * 64];
  __shared__ unsigned short lB[128 * 64];
  const int tid = threadIdx.x;
  const int wid = tid >> 6;
  const int lane = tid & 63;

  const int MG = 8;
  const int per = MG * Nt;
  const int g = blockIdx.x / per;
  const int rem = blockIdx.x - g * per;
  const int gsz = min(MG, Mt - g * MG);
  const int nIdx = rem / gsz;
  const int mIdx = g * MG + (rem - nIdx * gsz);
  const int bM = mIdx * 128;
  const int bN = nIdx * 128;
  const int wM = (wid >> 1) * 64;
  const int wN = (wid & 1) * 64;

  f32x4 acc[4][4];
#pragma unroll
  for (int i = 0; i < 4; ++i)
#pragma unroll
    for (int j = 0; j < 4; ++j) acc[i][j] = (f32x4){0.f, 0.f, 0.f, 0.f};

  const int mrow = wM + (lane & 15);
  const int nrow = wN + (lane & 15);
  const int q = lane >> 4;            // quad (k-offset within 32-K slice)
  const int swz = lane & 7;           // read-side swizzle key (== row&7 of frag row)
  const int srow = wid * 8 + (lane >> 3);        // staging row within 32-row band
  const int sc = (lane & 7) ^ (lane >> 3);       // fetched chunk (XOR swizzle)
  const int npass = A2 ? 2 : 1;

  for (int pass = 0; pass < npass; ++pass) {
    const unsigned short* Ap = pass ? A2 : A1;
    const unsigned short* Bp = pass ? B2 : B1;
    for (int k0 = 0; k0 < K; k0 += 64) {
#pragma unroll
      for (int r = 0; r < 4; ++r) {
        int row = r * 32 + srow;
        int ga = bM + row;
        if (ga >= M) ga = M - 1;                  // clamp: OOB rows never stored
        const unsigned short* gpA = Ap + (size_t)ga * K + k0 + sc * 8;
        const unsigned short* gpB = Bp + (size_t)(bN + row) * K + k0 + sc * 8;
        unsigned lo = (unsigned)(r * 32 + wid * 8) * 128;  // wave-uniform byte base
        __builtin_amdgcn_global_load_lds(
            (const __attribute__((address_space(1))) unsigned int*)gpA,
            (__attribute__((address_space(3))) unsigned int*)((char*)lA + lo), 16, 0, 0);
        __builtin_amdgcn_global_load_lds(
            (const __attribute__((address_space(1))) unsigned int*)gpB,
            (__attribute__((address_space(3))) unsigned int*)((char*)lB + lo), 16, 0, 0);
      }
      __syncthreads();
#pragma unroll
      for (int s = 0; s < 2; ++s) {
        const int cofs = ((s * 4 + q) ^ swz) * 8;
        short8 aF[4], bF[4];
#pragma unroll
        for (int i = 0; i < 4; ++i) {
          aF[i] = *(const short8*)&lA[(mrow + i * 16) * 64 + cofs];
          bF[i] = *(const short8*)&lB[(nrow + i * 16) * 64 + cofs];
        }
#pragma unroll
        for (int i = 0; i < 4; ++i)
#pragma unroll
          for (int j = 0; j < 4; ++j)
            acc[i][j] = __builtin_amdgcn_mfma_f32_16x16x32_bf16(aF[i], bF[j], acc[i][j], 0, 0, 0);
      }
      __syncthreads();
    }
  }

  // C/D layout: col = lane&15, row = (lane>>4)*4 + reg   [m89/m91]
  const int rbase = bM + wM + (lane >> 4) * 4;
#pragma unroll
  for (int i = 0; i < 4; ++i) {
#pragma unroll
    for (int r = 0; r < 4; ++r) {
      int row = rbase + i * 16 + r;
      if (row >= M) continue;
#pragma unroll
      for (int j = 0; j < 4; ++j) {
        int colN = bN + wN + j * 16 + (lane & 15);
        float v = acc[i][j][r];
        if (bias) v += bias[colN];
        if (doRelu) v = fmaxf(v, 0.f);
        Hout[(size_t)row * Nn + colN] = f2bf(v);
      }
    }
  }
}

// ---------------- layer 5 ----------------
// yz[v, 0:5] = h4[v]@Wl5, yz[v, 5:10] = h4[v]@Wr5   (fp32)
__global__ __launch_bounds__(64)
void gs_l5dot(const unsigned short* __restrict__ h4, const float* __restrict__ Wl,
              const float* __restrict__ Wr, float* __restrict__ yz) {
  __shared__ float sW[2560];
  const int v = blockIdx.x;
  const int l = threadIdx.x;
  for (int i = l; i < 2560; i += 64) sW[i] = (i < 1280) ? Wl[i] : Wr[i - 1280];
  __syncthreads();
  ushort4 u = ((const ushort4*)(h4 + (size_t)v * 256))[l];   // k = 4l..4l+3
  float hv[4] = {bf2f(u.x), bf2f(u.y), bf2f(u.z), bf2f(u.w)};
  float acc[10];
#pragma unroll
  for (int n = 0; n < 10; ++n) acc[n] = 0.f;
#pragma unroll
  for (int t = 0; t < 4; ++t) {
    int k = 4 * l + t;
#pragma unroll
    for (int n = 0; n < 5; ++n) {
      acc[n] += hv[t] * sW[k * 5 + n];
      acc[5 + n] += hv[t] * sW[1280 + k * 5 + n];
    }
  }
#pragma unroll
  for (int n = 0; n < 10; ++n)
    for (int off = 32; off > 0; off >>= 1) acc[n] += __shfl_down(acc[n], off, 64);
  if (l == 0) {
#pragma unroll
    for (int n = 0; n < 10; ++n) yz[(size_t)v * 10 + n] = acc[n];
  }
}

// out[v] = mean_{nb} y5[nb] + z5[v] + b  (no relu)
__global__ __launch_bounds__(64)
void gs_l5agg(const float* __restrict__ yz, const int* __restrict__ rp,
              const int* __restrict__ col, const float* __restrict__ b,
              float* __restrict__ out) {
  const int v = blockIdx.x;
  const int l = threadIdx.x;
  const int s0 = rp[v], s1 = rp[v + 1];
  const float inv = 1.0f / (float)max(s1 - s0, 1);
  float acc[5] = {0.f, 0.f, 0.f, 0.f, 0.f};
  for (int e = s0 + l; e < s1; e += 64) {
    const float* yr = yz + (size_t)col[e] * 10;
#pragma unroll
    for (int n = 0; n < 5; ++n) acc[n] += yr[n];
  }
#pragma unroll
  for (int n = 0; n < 5; ++n)
    for (int off = 32; off > 0; off >>= 1) acc[n] += __shfl_down(acc[n], off, 64);
  if (l == 0) {
#pragma unroll
    for (int n = 0; n < 5; ++n)
      out[(size_t)v * 5 + n] = acc[n] * inv + yz[(size_t)v * 10 + 5 + n] + b[n];
  }
}

// ---------------- launcher ----------------
extern "C" void kernel_launch(void* const* d_in, const int* in_sizes, int n_in,
                              void* d_out, int out_size, void* d_ws, size_t ws_size,
                              hipStream_t stream) {
  const float* x = (const float*)d_in[0];
  const int* ei = (const int*)d_in[1];
  const int N = in_sizes[0] / 768;
  const int E = in_sizes[1] / 2;
  const int* src = ei;
  const int* dst = ei + E;

  const float* Wl[5];
  const float* Wr[5];
  const float* bb[5];
  for (int l = 0; l < 5; ++l) {
    Wl[l] = (const float*)d_in[2 + 3 * l];
    Wr[l] = (const float*)d_in[3 + 3 * l];
    bb[l] = (const float*)d_in[4 + 3 * l];
  }

  char* w = (char*)d_ws;
  size_t off = 0;
  auto take = [&](size_t bytes) -> char* {
    char* p = w + off;
    off = (off + bytes + 255) & ~(size_t)255;
    return p;
  };
  // arenas (aliased over layer lifetime)
  unsigned short* ar1 = (unsigned short*)take((size_t)N * 768 * 2);   // xb -> C3
  unsigned short* ar2 = (unsigned short*)take((size_t)N * 768 * 2);   // aggb -> h2
  unsigned short* ar3 = (unsigned short*)take((size_t)N * 1536 * 2);  // h1 -> C4|h3|h4|yz5
  unsigned short* C2  = (unsigned short*)take((size_t)N * 1536 * 2);
  int* cnt  = (int*)take((size_t)N * 4);
  int* rp   = (int*)take((size_t)(N + 1) * 4);
  int* cur  = (int*)take((size_t)N * 4);
  int* col  = (int*)take((size_t)E * 4);
  const int nbChunks = (N + 1023) / 1024;
  int* bsum = (int*)take((size_t)(nbChunks + 1) * 4);
  unsigned short* WT1l = (unsigned short*)take((size_t)1536 * 768 * 2);
  unsigned short* WT1r = (unsigned short*)take((size_t)1536 * 768 * 2);
  unsigned short* WT2  = (unsigned short*)take((size_t)1536 * 1536 * 2);
  unsigned short* WT3  = (unsigned short*)take((size_t)768 * 768 * 2);
  unsigned short* WT4  = (unsigned short*)take((size_t)512 * 384 * 2);

  unsigned short* xb   = ar1;
  unsigned short* C3   = ar1;
  unsigned short* aggb = ar2;
  unsigned short* h2   = ar2;
  unsigned short* h1   = ar3;
  unsigned short* C4   = ar3;                                  // N x 512
  unsigned short* h3   = ar3 + (size_t)N * 512;                // N x 384
  unsigned short* h4   = ar3 + (size_t)N * (512 + 384);        // N x 256
  float*          yz5  = (float*)(ar3 + (size_t)N * (512 + 384 + 256)); // N x 10 f32

  const int M = N;
  const int Mt = (M + 127) / 128;

  // CSR build
  hipMemsetAsync(cnt, 0, (size_t)N * 4, stream);
  gs_count_deg<<<(E + 255) / 256, 256, 0, stream>>>(dst, cnt, E);
  gs_scanA<<<nbChunks, 256, 0, stream>>>(cnt, rp, bsum, N);
  gs_scanB<<<1, 64, 0, stream>>>(bsum, nbChunks);
  gs_scanC<<<(N + 256) / 256, 256, 0, stream>>>(rp, cur, bsum, N, nbChunks);
  gs_fill_csr<<<(E + 255) / 256, 256, 0, stream>>>(src, dst, cur, col, E);

  // conversions (all coalesced); batched transpose-pack (1 launch)
  gs_f32_to_bf16<<<((N * 768 / 4) + 255) / 256, 256, 0, stream>>>(x, xb, N * 768 / 4);
  TP8 tp;
  tp.t[0] = {Wl[0], WT1l, 768, 1536};
  tp.t[1] = {Wr[0], WT1r, 768, 1536};
  tp.t[2] = {Wl[1], WT2, 1536, 768};
  tp.t[3] = {Wr[1], WT2 + (size_t)768 * 1536, 1536, 768};
  tp.t[4] = {Wl[2], WT3, 768, 384};
  tp.t[5] = {Wr[2], WT3 + (size_t)384 * 768, 768, 384};
  tp.t[6] = {Wl[3], WT4, 384, 256};
  tp.t[7] = {Wr[3], WT4 + (size_t)256 * 384, 384, 256};
  gs_tpack8<<<dim3(48, 48, 8), dim3(32, 8), 0, stream>>>(tp);

  float* houtF = (float*)d_out;                 // [N,256] fp32
  float* out5  = (float*)d_out + (size_t)N * 256;

  // L1: agg-before (Fin 768 < Fout 1536), dual GEMM -> h1 (relu+bias)
  gs_agg_wide<<<dim3(N, 2), 64, 0, stream>>>(xb, 768, -1, rp, col, nullptr, aggb, nullptr, 768, 0);
  gs_gemm<<<Mt * 12, 256, 0, stream>>>(aggb, xb, WT1l, WT1r, bb[0], h1, M, 1536, 768, 1, Mt, 12);

  // L2: GEMM C2 = h1 @ [Wl2|Wr2]  (N x 1536), fused wide agg over 768 -> h2
  gs_gemm<<<Mt * 12, 256, 0, stream>>>(h1, nullptr, WT2, nullptr, nullptr, C2, M, 1536, 1536, 0, Mt, 12);
  gs_agg_wide<<<dim3(N, 2), 64, 0, stream>>>(C2, 1536, 768, rp, col, bb[1], h2, nullptr, 768, 1);

  // L3: GEMM C3 = h2 @ [Wl3|Wr3]  (N x 768), fused wide agg over 384 -> h3
  gs_gemm<<<Mt * 6, 256, 0, stream>>>(h2, nullptr, WT3, nullptr, nullptr, C3, M, 768, 768, 0, Mt, 6);
  gs_agg_wide<<<dim3(N, 1), 64, 0, stream>>>(C3, 768, 384, rp, col, bb[2], h3, nullptr, 384, 1);

  // L4: GEMM C4 = h3 @ [Wl4|Wr4]  (N x 512), fused wide agg over 256 -> h4 (bf16) + d_out (fp32)
  gs_gemm<<<Mt * 4, 256, 0, stream>>>(h3, nullptr, WT4, nullptr, nullptr, C4, M, 512, 384, 0, Mt, 4);
  gs_agg_wide<<<dim3(N, 1), 64, 0, stream>>>(C4, 512, 256, rp, col, bb[3], h4, houtF, 256, 1);

  // L5: per-node dot -> yz5 [N,10] fp32, then tiny agg over 5 -> out
  gs_l5dot<<<N, 64, 0, stream>>>(h4, Wl[4], Wr[4], yz5);
  gs_l5agg<<<N, 64, 0, stream>>>(yz5, rp, col, bb[4], out5);
}